// Round 10
// baseline (189.434 us; speedup 1.0000x reference)
//
#include <hip/hip_runtime.h>

typedef unsigned short u16;
typedef unsigned int u32;
typedef __attribute__((ext_vector_type(8))) __bf16 bf16x8;
typedef __attribute__((ext_vector_type(4))) float f32x4;

#define L_SEQ 2048
#define NROWS 4096
#define NHEAD 8
#define SWIN 33

__device__ __forceinline__ u16 f2b(float f) {
  u32 u = __float_as_uint(f);
  u += 0x7fffu + ((u >> 16) & 1u);
  return (u16)(u >> 16);
}
__device__ __forceinline__ float b2f(u32 lo16) { return __uint_as_float(lo16 << 16); }

__device__ __forceinline__ float sigmoidf_(float x) { return 1.f / (1.f + expf(-x)); }
__device__ __forceinline__ float siluf_(float x) { return x / (1.f + expf(-x)); }

__device__ __forceinline__ void gload_lds16(void* g, void* l) {
  __builtin_amdgcn_global_load_lds((__attribute__((address_space(1))) void*)g,
                                   (__attribute__((address_space(3))) void*)l, 16, 0, 0);
}

// ---------------- fused: fp32 wave projection (blocks < 1024) + weight fp32->bf16 (blocks >= 1024) ----------------
// params layout per row (18 floats): [0..7]=freq, [8..15]=decay, [16]=freq_avg, [17]=phase_avg
// RPB=4: 1024 blocks = 4/CU occupancy for the latency-bound shfl chains (R6 post-mortem);
// R8 post-mortem: do NOT fuse MFMA paths into this kernel — static LDS is unioned across
// paths and crushed wave-params occupancy (41 KB/block -> 3 blocks/CU, +7 us net).
#define RPB 4
__global__ __launch_bounds__(256) void wave_params_kernel(
    const float* __restrict__ x, const float* __restrict__ w_wave,
    const float* __restrict__ b_wave, float* __restrict__ params,
    u16* __restrict__ xb,
    const float* __restrict__ wq, const float* __restrict__ w1,
    const float* __restrict__ w2, const float* __restrict__ wo,
    u16* __restrict__ wqb, u16* __restrict__ w1b, u16* __restrict__ w2b,
    u16* __restrict__ wob) {
  __shared__ float xs[RPB][1024];
  __shared__ float wp[RPB][24];
  const int t = threadIdx.x;
  const int bx = blockIdx.x;
  if (bx >= 1024) {  // -------- weight-convert path --------
    size_t i = (size_t)(bx - 1024) * 256 + t;  // index over groups of 4
    const float* src;
    u16* dst;
    if (i < 32768) { src = wq; dst = wqb; }
    else if ((i -= 32768) < 65536) { src = w1; dst = w1b; }
    else if ((i -= 65536) < 65536) { src = w2; dst = w2b; }
    else if ((i -= 65536) < 262144) { src = wo; dst = wob; }
    else return;
    const float4 v = *(const float4*)(src + i * 4);
    uint2 pk;
    pk.x = (u32)f2b(v.x) | ((u32)f2b(v.y) << 16);
    pk.y = (u32)f2b(v.z) | ((u32)f2b(v.w) << 16);
    *(uint2*)(dst + i * 4) = pk;
    return;
  }
  const int row0 = bx * RPB;
  const float4* xv = (const float4*)(x + (size_t)row0 * 1024);
  float4* xsv = (float4*)&xs[0][0];
  uint2* xbv = (uint2*)(xb + (size_t)row0 * 1024);
#pragma unroll
  for (int i = 0; i < RPB; ++i) {
    const float4 v = xv[t + 256 * i];
    xsv[t + 256 * i] = v;
    uint2 pk;
    pk.x = (u32)f2b(v.x) | ((u32)f2b(v.y) << 16);
    pk.y = (u32)f2b(v.z) | ((u32)f2b(v.w) << 16);
    xbv[t + 256 * i] = pk;
  }
  __syncthreads();
  const int wv = t >> 6, lane = t & 63;
#pragma unroll
  for (int oi = 0; oi < 6; ++oi) {
    const int o = wv * 6 + oi;
    float w[16];
#pragma unroll
    for (int k = 0; k < 16; ++k) w[k] = w_wave[o * 1024 + lane + 64 * k];
    const float bo = b_wave[o];
    float d[RPB];
#pragma unroll
    for (int r = 0; r < RPB; ++r) {
      d[r] = 0.f;
#pragma unroll
      for (int k = 0; k < 16; ++k) d[r] += w[k] * xs[r][lane + 64 * k];
    }
#pragma unroll
    for (int r = 0; r < RPB; ++r) {
#pragma unroll
      for (int off = 32; off; off >>= 1) d[r] += __shfl_xor(d[r], off);
    }
    if (lane == 0) {
#pragma unroll
      for (int r = 0; r < RPB; ++r) wp[r][o] = siluf_(d[r] + bo);
    }
  }
  __syncthreads();
  if (t < RPB * 8) {
    const int r = t >> 3, h = t & 7;
    float* pr = params + (size_t)(row0 + r) * 18;
    pr[h] = sigmoidf_(wp[r][h]) * 15.f + 1.f;
    pr[8 + h] = sigmoidf_(wp[r][16 + h]) * 9.5f + 0.5f;
  }
  if (t < RPB) {
    float fs = 0.f, ps = 0.f;
    for (int h = 0; h < 8; ++h) {
      fs += sigmoidf_(wp[t][h]);
      ps += tanhf(wp[t][8 + h]);
    }
    float* pr = params + (size_t)(row0 + t) * 18;
    pr[16] = fs * (15.f / 8.f) + 1.f;
    pr[17] = ps * (16.f / 8.f);
  }
}

// ---------------- bf16 MFMA GEMM, C = epilogue(A @ W^T) ----------------
// TM x TN tile, BK=64, 2x2 wave grid, ping-pong LDS double buffer, XOR-swizzled 16B chunks.
// MODE 1: silu(acc+bias) -> bf16; 2: sigmoid(acc+bias)*aux(bf16) -> bf16; 3: acc -> f32;
// MODE 4 (TN=32): qk[row][h] = sum_p silu(acc+bias)*wkey[p] -> f32 (frow shfl-reduce)
// ENT=1: blocks with bn == gridDim.y-1 do the 4096->1 entropy reduce instead (bm==0 only).
template <int MODE, int TM, int TN, int BK, int ENT = 0>
__global__ __launch_bounds__(256) void gemm_bt(
    const u16* __restrict__ A, const u16* __restrict__ Bw,
    const float* __restrict__ bias, const u16* __restrict__ aux,
    const float* __restrict__ wkey, const float* __restrict__ entpart,
    float* __restrict__ entslot, void* __restrict__ outp, int N, int K) {
  __shared__ __align__(16) u16 As[2 * TM * BK];
  __shared__ __align__(16) u16 Bs[2 * TN * BK];
  const int t = threadIdx.x;
  const int bm = blockIdx.x, bn = blockIdx.y;
  if (ENT && bn == (int)gridDim.y - 1) {  // entropy reduce slice (folded dispatch)
    if (bm != 0) return;
    __shared__ float ws2[4];
    float s = 0.f;
#pragma unroll
    for (int i = 0; i < 16; ++i) s += entpart[t + 256 * i];
#pragma unroll
    for (int o = 32; o; o >>= 1) s += __shfl_xor(s, o);
    if ((t & 63) == 0) ws2[t >> 6] = s;
    __syncthreads();
    if (t == 0) *entslot = ws2[0] + ws2[1] + ws2[2] + ws2[3];
    return;
  }
  constexpr int TPR = BK / 8;      // threads (16B chunks) per row
  constexpr int RPP = 256 / TPR;   // rows per staging pass
  const int rowS = t / TPR;
  const int colX = ((t & (TPR - 1)) ^ (rowS & (TPR - 1))) * 8;  // swizzled source column
  const u16* Ag = A + (size_t)(bm * TM + rowS) * K + colX;
  const u16* Bg = Bw + (size_t)(bn * TN + rowS) * K + colX;
  constexpr int NI = TM / 32, NJ = TN / 32;
  f32x4 acc[NI][NJ] = {};
  const int lane = t & 63, wv = t >> 6;
  const int wm = (wv >> 1) * (TM / 2);
  const int wn = (wv & 1) * (TN / 2);
  const int frow = lane & 15, quad = lane >> 4;
  auto stage = [&](int buf, int kt) {
    char* Ab = (char*)As + buf * (TM * BK * 2);
    char* Bb = (char*)Bs + buf * (TN * BK * 2);
#pragma unroll
    for (int r = 0; r < TM; r += RPP)
      gload_lds16((void*)(Ag + kt + (size_t)r * K), Ab + r * BK * 2 + t * 16);
#pragma unroll
    for (int r = 0; r < TN; r += RPP)
      gload_lds16((void*)(Bg + kt + (size_t)r * K), Bb + r * BK * 2 + t * 16);
  };
  stage(0, 0);
  int pb = 0;
  for (int kt = 0; kt < K; kt += BK, pb ^= 1) {
    __syncthreads();  // drains DMAs for buf pb (issued one compute-phase ago)
    if (kt + BK < K) stage(pb ^ 1, kt + BK);
#pragma unroll
    for (int kk = 0; kk < BK; kk += 32) {
      bf16x8 af[NI], bfr[NJ];
#pragma unroll
      for (int i = 0; i < NI; ++i) {
        const int rr = wm + i * 16 + frow;
        af[i] = *(bf16x8*)&As[pb * TM * BK + rr * BK + ((((kk >> 3) + quad) ^ (rr & (TPR - 1))) * 8)];
      }
#pragma unroll
      for (int j = 0; j < NJ; ++j) {
        const int rr = wn + j * 16 + frow;
        bfr[j] = *(bf16x8*)&Bs[pb * TN * BK + rr * BK + ((((kk >> 3) + quad) ^ (rr & (TPR - 1))) * 8)];
      }
#pragma unroll
      for (int i = 0; i < NI; ++i)
#pragma unroll
        for (int j = 0; j < NJ; ++j)
          acc[i][j] = __builtin_amdgcn_mfma_f32_16x16x32_bf16(af[i], bfr[j], acc[i][j], 0, 0, 0);
    }
  }
  if (MODE == 4) {
    // qk epilogue: each 16-col C group = one head's 16 POS values across frow lanes.
    const float bq = bias[bn * TN + wn + frow];
    const float wkf = wkey[frow];
    const int h = bn * 2 + (wn >> 4);
#pragma unroll
    for (int i = 0; i < NI; ++i)
#pragma unroll
      for (int r = 0; r < 4; ++r) {
        float w = siluf_(acc[i][0][r] + bq) * wkf;
        w += __shfl_xor(w, 1); w += __shfl_xor(w, 2);
        w += __shfl_xor(w, 4); w += __shfl_xor(w, 8);
        if (frow == 0) {
          const int gm = bm * TM + wm + i * 16 + quad * 4 + r;
          ((float*)outp)[gm * 8 + h] = w;
        }
      }
    return;
  }
#pragma unroll
  for (int i = 0; i < NI; ++i)
#pragma unroll
    for (int j = 0; j < NJ; ++j)
#pragma unroll
      for (int r = 0; r < 4; ++r) {
        const int gm = bm * TM + wm + i * 16 + quad * 4 + r;
        const int gn = bn * TN + wn + j * 16 + frow;
        float v = acc[i][j][r];
        const size_t o = (size_t)gm * N + gn;
        if (MODE == 1) { v = siluf_(v + bias[gn]); ((u16*)outp)[o] = f2b(v); }
        if (MODE == 2) { v = sigmoidf_(v + bias[gn]) * b2f(aux[o]); ((u16*)outp)[o] = f2b(v); }
        if (MODE == 3) { ((float*)outp)[o] = v; }
      }
}

// ---------------- attention: softmax/envelope weights + bf16 gather-weighted sum ----------------
// __launch_bounds__(256, 2): give the register allocator room (~130 VGPR) to keep
// all 33 gather loads in flight (R3 post-mortem: default bounds pinned VGPR=32).
__global__ __launch_bounds__(256, 2) void attn_kernel(
    const u16* __restrict__ xb, const float* __restrict__ params,
    const float* __restrict__ qkbuf, u16* __restrict__ outb,
    float* __restrict__ entpart) {
  __shared__ float pf[18];
  __shared__ float qkL[8];
  __shared__ int idxL[SWIN];
  __shared__ int validL[SWIN];
  __shared__ float attnL[NHEAD][SWIN];
  __shared__ float entW[4];
  const int t = threadIdx.x;
  const int bx = blockIdx.x;
  const int row = ((bx & 7) << 9) | (bx >> 3);  // XCD-contiguous l ranges for L2 locality
  const int b = row >> 11, l = row & 2047;
  if (t < 18) pf[t] = params[(size_t)row * 18 + t];
  if (t >= 64 && t < 72) qkL[t - 64] = qkbuf[(size_t)row * 8 + (t - 64)] * 0.25f;  // * POS^-0.5
  __syncthreads();
  if (t < SWIN) {
    const float pos = (float)l + (float)(t - 16) * pf[16] + pf[17];
    validL[t] = (pos >= 0.f) && (pos < (float)L_SEQ);
    int id = (int)pos;  // trunc toward zero, same as astype(int32)
    idxL[t] = min(max(id, 0), L_SEQ - 1);
  }
  __syncthreads();
  const int wv = t >> 6, lane = t & 63;
  float entacc = 0.f;
#pragma unroll
  for (int it = 0; it < 2; ++it) {
    const int h = wv + 4 * it;
    const bool act = lane < SWIN;
    const int s = act ? lane : 0;
    const float rel = fabsf((float)(s - 16)) * pf[h];
    const float logit = rel * qkL[h];
    const bool vs = act && validL[s];
    float m = vs ? logit : -INFINITY;
#pragma unroll
    for (int o = 32; o; o >>= 1) m = fmaxf(m, __shfl_xor(m, o));
    float p = vs ? expf(logit - m) : 0.f;
    float sm = p;
#pragma unroll
    for (int o = 32; o; o >>= 1) sm += __shfl_xor(sm, o);
    const float soft = sm > 0.f ? p / sm : 0.f;
    const float env = expf(-rel / fmaxf(pf[8 + h], 0.1f));
    float a = soft * env;
    float as = a;
#pragma unroll
    for (int o = 32; o; o >>= 1) as += __shfl_xor(as, o);
    a = a / (as + 1e-8f);
    if (act) attnL[h][s] = a;  // exactly 0 for invalid s
    float et = a * logf(a + 1e-8f);
#pragma unroll
    for (int o = 32; o; o >>= 1) et += __shfl_xor(et, o);
    entacc += et;
  }
  if (lane == 0) entW[wv] = entacc;
  __syncthreads();
  // entropy partial: per-block store (atomic version was a 63 us serialization floor)
  if (t == 0) entpart[bx] = (entW[0] + entW[1] + entW[2] + entW[3]) * (1.f / 32768.f);
  // bf16 gather: thread t handles channels [4t,4t+4) (one uint2 / sample), head t>>5.
  // Two-chunk pipeline (17/16): all 33 loads issued before the first FMA wait.
  const u16* xbase = xb + (size_t)b * L_SEQ * 1024 + 4 * t;
  const int h = t >> 5;
  float4 acc = make_float4(0.f, 0.f, 0.f, 0.f);
  uint2 v0[17], v1[16];
#pragma unroll
  for (int k = 0; k < 17; ++k) v0[k] = *(const uint2*)(xbase + (size_t)idxL[k] * 1024);
  __builtin_amdgcn_sched_barrier(0);
#pragma unroll
  for (int k = 0; k < 16; ++k) v1[k] = *(const uint2*)(xbase + (size_t)idxL[17 + k] * 1024);
  __builtin_amdgcn_sched_barrier(0);
#pragma unroll
  for (int k = 0; k < 17; ++k) {
    const float a_ = attnL[h][k];
    acc.x += a_ * b2f(v0[k].x & 0xffffu);
    acc.y += a_ * b2f(v0[k].x >> 16);
    acc.z += a_ * b2f(v0[k].y & 0xffffu);
    acc.w += a_ * b2f(v0[k].y >> 16);
  }
  __builtin_amdgcn_sched_barrier(0);
#pragma unroll
  for (int k = 0; k < 16; ++k) {
    const float a_ = attnL[h][17 + k];
    acc.x += a_ * b2f(v1[k].x & 0xffffu);
    acc.y += a_ * b2f(v1[k].x >> 16);
    acc.z += a_ * b2f(v1[k].y & 0xffffu);
    acc.w += a_ * b2f(v1[k].y >> 16);
  }
  const size_t o4 = (size_t)row * 1024 + 4 * t;
  uint2 pk;
  pk.x = (u32)f2b(acc.x) | ((u32)f2b(acc.y) << 16);
  pk.y = (u32)f2b(acc.z) | ((u32)f2b(acc.w) << 16);
  *(uint2*)(outb + o4) = pk;
}

extern "C" void kernel_launch(void* const* d_in, const int* in_sizes, int n_in,
                              void* d_out, int out_size, void* d_ws, size_t ws_size,
                              hipStream_t stream) {
  const float* x = (const float*)d_in[0];
  const float* w_wave = (const float*)d_in[1];
  const float* b_wave = (const float*)d_in[2];
  const float* w_query = (const float*)d_in[3];
  const float* b_query = (const float*)d_in[4];
  const float* w_key = (const float*)d_in[5];
  const float* w_out = (const float*)d_in[6];
  const float* w_se1 = (const float*)d_in[7];
  const float* b_se1 = (const float*)d_in[8];
  const float* w_se2 = (const float*)d_in[9];
  const float* b_se2 = (const float*)d_in[10];
  float* out = (float*)d_out;
  char* ws = (char*)d_ws;
  size_t off = 0;
  auto alloc = [&](size_t bytes) { void* p = ws + off; off += (bytes + 255) & ~(size_t)255; return p; };
  float* params = (float*)alloc(NROWS * 18 * 4);
  float* qkbuf = (float*)alloc((size_t)NROWS * 8 * 4);
  float* entpart = (float*)alloc(NROWS * 4);
  u16* outb = (u16*)alloc((size_t)NROWS * 1024 * 2);
  u16* t1b = (u16*)alloc((size_t)NROWS * 256 * 2);
  u16* gb = (u16*)alloc((size_t)NROWS * 1024 * 2);
  u16* xb = (u16*)alloc((size_t)NROWS * 1024 * 2);
  u16* wqb = (u16*)alloc(128 * 1024 * 2);
  u16* w1b = (u16*)alloc(256 * 1024 * 2);
  u16* w2b = (u16*)alloc(1024 * 256 * 2);
  u16* wob = (u16*)alloc((size_t)1024 * 1024 * 2);
  float* entslot = out + (out_size - 1);

  // blocks [0,1024) = wave params + x->bf16; blocks [1024, 1024+1664) = weight converts
  wave_params_kernel<<<dim3(1024 + 1664), 256, 0, stream>>>(
      x, w_wave, b_wave, params, xb, w_query, w_se1, w_se2, w_out, wqb, w1b, w2b, wob);
  gemm_bt<4, 64, 32, 64><<<dim3(64, 4), 256, 0, stream>>>(
      xb, wqb, b_query, nullptr, w_key, nullptr, nullptr, qkbuf, 128, 1024);
  attn_kernel<<<dim3(NROWS), 256, 0, stream>>>(xb, params, qkbuf, outb, entpart);
  gemm_bt<1, 64, 64, 64, 1><<<dim3(64, 5), 256, 0, stream>>>(
      outb, w1b, b_se1, nullptr, nullptr, entpart, entslot, t1b, 256, 1024);
  gemm_bt<2, 128, 128, 64><<<dim3(32, 8), 256, 0, stream>>>(
      t1b, w2b, b_se2, outb, nullptr, nullptr, nullptr, gb, 1024, 256);
  gemm_bt<3, 128, 128, 64><<<dim3(32, 8), 256, 0, stream>>>(
      gb, wob, nullptr, nullptr, nullptr, nullptr, nullptr, out, 1024, 1024);
}

// Round 11
// 181.953 us; speedup vs baseline: 1.0411x; 1.0411x over previous
//
#include <hip/hip_runtime.h>

typedef unsigned short u16;
typedef unsigned int u32;
typedef __attribute__((ext_vector_type(8))) __bf16 bf16x8;
typedef __attribute__((ext_vector_type(4))) float f32x4;

#define L_SEQ 2048
#define NROWS 4096
#define NHEAD 8
#define SWIN 33

__device__ __forceinline__ u16 f2b(float f) {
  u32 u = __float_as_uint(f);
  u += 0x7fffu + ((u >> 16) & 1u);
  return (u16)(u >> 16);
}
__device__ __forceinline__ float b2f(u32 lo16) { return __uint_as_float(lo16 << 16); }

__device__ __forceinline__ float sigmoidf_(float x) { return 1.f / (1.f + expf(-x)); }
__device__ __forceinline__ float siluf_(float x) { return x / (1.f + expf(-x)); }

__device__ __forceinline__ void gload_lds16(void* g, void* l) {
  __builtin_amdgcn_global_load_lds((__attribute__((address_space(1))) void*)g,
                                   (__attribute__((address_space(3))) void*)l, 16, 0, 0);
}

// ---------------- fused: fp32 wave projection (blocks < 2048) + weight fp32->bf16 (blocks >= 2048) ----------------
// params layout per row (18 floats): [0..7]=freq, [8..15]=decay, [16]=freq_avg, [17]=phase_avg
// RPB=2: 2048 blocks = 8/CU occupancy over the latency-bound shfl reduce chains
// (R6/R7 ladder: RPB 8->4 doubled occupancy, 68->~25 us; this doubles again).
// fp32 kept: bf16 projection perturbs sample_pos -> gather index flips.
// R8 post-mortem: never fuse MFMA paths here — static LDS unions across paths.
#define RPB 2
__global__ __launch_bounds__(256) void wave_params_kernel(
    const float* __restrict__ x, const float* __restrict__ w_wave,
    const float* __restrict__ b_wave, float* __restrict__ params,
    u16* __restrict__ xb,
    const float* __restrict__ wq, const float* __restrict__ w1,
    const float* __restrict__ w2, const float* __restrict__ wo,
    u16* __restrict__ wqb, u16* __restrict__ w1b, u16* __restrict__ w2b,
    u16* __restrict__ wob) {
  __shared__ float xs[RPB][1024];
  __shared__ float wp[RPB][24];
  const int t = threadIdx.x;
  const int bx = blockIdx.x;
  if (bx >= 2048) {  // -------- weight-convert path --------
    size_t i = (size_t)(bx - 2048) * 256 + t;  // index over groups of 4
    const float* src;
    u16* dst;
    if (i < 32768) { src = wq; dst = wqb; }
    else if ((i -= 32768) < 65536) { src = w1; dst = w1b; }
    else if ((i -= 65536) < 65536) { src = w2; dst = w2b; }
    else if ((i -= 65536) < 262144) { src = wo; dst = wob; }
    else return;
    const float4 v = *(const float4*)(src + i * 4);
    uint2 pk;
    pk.x = (u32)f2b(v.x) | ((u32)f2b(v.y) << 16);
    pk.y = (u32)f2b(v.z) | ((u32)f2b(v.w) << 16);
    *(uint2*)(dst + i * 4) = pk;
    return;
  }
  const int row0 = bx * RPB;
  const float4* xv = (const float4*)(x + (size_t)row0 * 1024);
  float4* xsv = (float4*)&xs[0][0];
  uint2* xbv = (uint2*)(xb + (size_t)row0 * 1024);
#pragma unroll
  for (int i = 0; i < RPB; ++i) {
    const float4 v = xv[t + 256 * i];
    xsv[t + 256 * i] = v;
    uint2 pk;
    pk.x = (u32)f2b(v.x) | ((u32)f2b(v.y) << 16);
    pk.y = (u32)f2b(v.z) | ((u32)f2b(v.w) << 16);
    xbv[t + 256 * i] = pk;
  }
  __syncthreads();
  const int wv = t >> 6, lane = t & 63;
#pragma unroll
  for (int oi = 0; oi < 6; ++oi) {
    const int o = wv * 6 + oi;
    float w[16];
#pragma unroll
    for (int k = 0; k < 16; ++k) w[k] = w_wave[o * 1024 + lane + 64 * k];
    const float bo = b_wave[o];
    float d[RPB];
#pragma unroll
    for (int r = 0; r < RPB; ++r) {
      d[r] = 0.f;
#pragma unroll
      for (int k = 0; k < 16; ++k) d[r] += w[k] * xs[r][lane + 64 * k];
    }
#pragma unroll
    for (int r = 0; r < RPB; ++r) {
#pragma unroll
      for (int off = 32; off; off >>= 1) d[r] += __shfl_xor(d[r], off);
    }
    if (lane == 0) {
#pragma unroll
      for (int r = 0; r < RPB; ++r) wp[r][o] = siluf_(d[r] + bo);
    }
  }
  __syncthreads();
  if (t < RPB * 8) {
    const int r = t >> 3, h = t & 7;
    float* pr = params + (size_t)(row0 + r) * 18;
    pr[h] = sigmoidf_(wp[r][h]) * 15.f + 1.f;
    pr[8 + h] = sigmoidf_(wp[r][16 + h]) * 9.5f + 0.5f;
  }
  if (t < RPB) {
    float fs = 0.f, ps = 0.f;
    for (int h = 0; h < 8; ++h) {
      fs += sigmoidf_(wp[t][h]);
      ps += tanhf(wp[t][8 + h]);
    }
    float* pr = params + (size_t)(row0 + t) * 18;
    pr[16] = fs * (15.f / 8.f) + 1.f;
    pr[17] = ps * (16.f / 8.f);
  }
}

// ---------------- bf16 MFMA GEMM, C = epilogue(A @ W^T) ----------------
// TM x TN tile, BK=64, 2x2 wave grid, ping-pong LDS double buffer, XOR-swizzled 16B chunks.
// R9 post-mortem rule: keep LDS <= 48 KB so >= 2 blocks/CU stay resident (128x128
// dbuf = 64 KB -> 1 block/CU -> nothing covers the barrier drain; cost +7 us).
// MODE 1: silu(acc+bias) -> bf16; 2: sigmoid(acc+bias)*aux(bf16) -> bf16; 3: acc -> f32;
// MODE 4 (TN=32): qk[row][h] = sum_p silu(acc+bias)*wkey[p] -> f32 (frow shfl-reduce)
// ENT=1: blocks with bn == gridDim.y-1 do the 4096->1 entropy reduce instead (bm==0 only).
template <int MODE, int TM, int TN, int BK, int ENT = 0>
__global__ __launch_bounds__(256) void gemm_bt(
    const u16* __restrict__ A, const u16* __restrict__ Bw,
    const float* __restrict__ bias, const u16* __restrict__ aux,
    const float* __restrict__ wkey, const float* __restrict__ entpart,
    float* __restrict__ entslot, void* __restrict__ outp, int N, int K) {
  __shared__ __align__(16) u16 As[2 * TM * BK];
  __shared__ __align__(16) u16 Bs[2 * TN * BK];
  const int t = threadIdx.x;
  const int bm = blockIdx.x, bn = blockIdx.y;
  if (ENT && bn == (int)gridDim.y - 1) {  // entropy reduce slice (folded dispatch)
    if (bm != 0) return;
    __shared__ float ws2[4];
    float s = 0.f;
#pragma unroll
    for (int i = 0; i < 16; ++i) s += entpart[t + 256 * i];
#pragma unroll
    for (int o = 32; o; o >>= 1) s += __shfl_xor(s, o);
    if ((t & 63) == 0) ws2[t >> 6] = s;
    __syncthreads();
    if (t == 0) *entslot = ws2[0] + ws2[1] + ws2[2] + ws2[3];
    return;
  }
  constexpr int TPR = BK / 8;      // threads (16B chunks) per row
  constexpr int RPP = 256 / TPR;   // rows per staging pass
  const int rowS = t / TPR;
  const int colX = ((t & (TPR - 1)) ^ (rowS & (TPR - 1))) * 8;  // swizzled source column
  const u16* Ag = A + (size_t)(bm * TM + rowS) * K + colX;
  const u16* Bg = Bw + (size_t)(bn * TN + rowS) * K + colX;
  constexpr int NI = TM / 32, NJ = TN / 32;
  f32x4 acc[NI][NJ] = {};
  const int lane = t & 63, wv = t >> 6;
  const int wm = (wv >> 1) * (TM / 2);
  const int wn = (wv & 1) * (TN / 2);
  const int frow = lane & 15, quad = lane >> 4;
  auto stage = [&](int buf, int kt) {
    char* Ab = (char*)As + buf * (TM * BK * 2);
    char* Bb = (char*)Bs + buf * (TN * BK * 2);
#pragma unroll
    for (int r = 0; r < TM; r += RPP)
      gload_lds16((void*)(Ag + kt + (size_t)r * K), Ab + r * BK * 2 + t * 16);
#pragma unroll
    for (int r = 0; r < TN; r += RPP)
      gload_lds16((void*)(Bg + kt + (size_t)r * K), Bb + r * BK * 2 + t * 16);
  };
  stage(0, 0);
  int pb = 0;
  for (int kt = 0; kt < K; kt += BK, pb ^= 1) {
    __syncthreads();  // drains DMAs for buf pb (issued one compute-phase ago)
    if (kt + BK < K) stage(pb ^ 1, kt + BK);
#pragma unroll
    for (int kk = 0; kk < BK; kk += 32) {
      bf16x8 af[NI], bfr[NJ];
#pragma unroll
      for (int i = 0; i < NI; ++i) {
        const int rr = wm + i * 16 + frow;
        af[i] = *(bf16x8*)&As[pb * TM * BK + rr * BK + ((((kk >> 3) + quad) ^ (rr & (TPR - 1))) * 8)];
      }
#pragma unroll
      for (int j = 0; j < NJ; ++j) {
        const int rr = wn + j * 16 + frow;
        bfr[j] = *(bf16x8*)&Bs[pb * TN * BK + rr * BK + ((((kk >> 3) + quad) ^ (rr & (TPR - 1))) * 8)];
      }
#pragma unroll
      for (int i = 0; i < NI; ++i)
#pragma unroll
        for (int j = 0; j < NJ; ++j)
          acc[i][j] = __builtin_amdgcn_mfma_f32_16x16x32_bf16(af[i], bfr[j], acc[i][j], 0, 0, 0);
    }
  }
  if (MODE == 4) {
    // qk epilogue: each 16-col C group = one head's 16 POS values across frow lanes.
    const float bq = bias[bn * TN + wn + frow];
    const float wkf = wkey[frow];
    const int h = bn * 2 + (wn >> 4);
#pragma unroll
    for (int i = 0; i < NI; ++i)
#pragma unroll
      for (int r = 0; r < 4; ++r) {
        float w = siluf_(acc[i][0][r] + bq) * wkf;
        w += __shfl_xor(w, 1); w += __shfl_xor(w, 2);
        w += __shfl_xor(w, 4); w += __shfl_xor(w, 8);
        if (frow == 0) {
          const int gm = bm * TM + wm + i * 16 + quad * 4 + r;
          ((float*)outp)[gm * 8 + h] = w;
        }
      }
    return;
  }
#pragma unroll
  for (int i = 0; i < NI; ++i)
#pragma unroll
    for (int j = 0; j < NJ; ++j)
#pragma unroll
      for (int r = 0; r < 4; ++r) {
        const int gm = bm * TM + wm + i * 16 + quad * 4 + r;
        const int gn = bn * TN + wn + j * 16 + frow;
        float v = acc[i][j][r];
        const size_t o = (size_t)gm * N + gn;
        if (MODE == 1) { v = siluf_(v + bias[gn]); ((u16*)outp)[o] = f2b(v); }
        if (MODE == 2) { v = sigmoidf_(v + bias[gn]) * b2f(aux[o]); ((u16*)outp)[o] = f2b(v); }
        if (MODE == 3) { ((float*)outp)[o] = v; }
      }
}

// ---------------- attention: softmax/envelope weights + bf16 gather-weighted sum ----------------
// __launch_bounds__(256, 4): gather live set is ~66 VGPR (33 x uint2) + ~40 overhead
// <= 128-cap, so 4 waves/EU fit -> 4 blocks/CU (R3: default bounds pinned VGPR=32 and
// serialized; R5's (256,2) fixed ILP, this doubles the TLP on top).
__global__ __launch_bounds__(256, 4) void attn_kernel(
    const u16* __restrict__ xb, const float* __restrict__ params,
    const float* __restrict__ qkbuf, u16* __restrict__ outb,
    float* __restrict__ entpart) {
  __shared__ float pf[18];
  __shared__ float qkL[8];
  __shared__ int idxL[SWIN];
  __shared__ int validL[SWIN];
  __shared__ float attnL[NHEAD][SWIN];
  __shared__ float entW[4];
  const int t = threadIdx.x;
  const int bx = blockIdx.x;
  const int row = ((bx & 7) << 9) | (bx >> 3);  // XCD-contiguous l ranges for L2 locality
  const int b = row >> 11, l = row & 2047;
  if (t < 18) pf[t] = params[(size_t)row * 18 + t];
  if (t >= 64 && t < 72) qkL[t - 64] = qkbuf[(size_t)row * 8 + (t - 64)] * 0.25f;  // * POS^-0.5
  __syncthreads();
  if (t < SWIN) {
    const float pos = (float)l + (float)(t - 16) * pf[16] + pf[17];
    validL[t] = (pos >= 0.f) && (pos < (float)L_SEQ);
    int id = (int)pos;  // trunc toward zero, same as astype(int32)
    idxL[t] = min(max(id, 0), L_SEQ - 1);
  }
  __syncthreads();
  const int wv = t >> 6, lane = t & 63;
  float entacc = 0.f;
#pragma unroll
  for (int it = 0; it < 2; ++it) {
    const int h = wv + 4 * it;
    const bool act = lane < SWIN;
    const int s = act ? lane : 0;
    const float rel = fabsf((float)(s - 16)) * pf[h];
    const float logit = rel * qkL[h];
    const bool vs = act && validL[s];
    float m = vs ? logit : -INFINITY;
#pragma unroll
    for (int o = 32; o; o >>= 1) m = fmaxf(m, __shfl_xor(m, o));
    float p = vs ? expf(logit - m) : 0.f;
    float sm = p;
#pragma unroll
    for (int o = 32; o; o >>= 1) sm += __shfl_xor(sm, o);
    const float soft = sm > 0.f ? p / sm : 0.f;
    const float env = expf(-rel / fmaxf(pf[8 + h], 0.1f));
    float a = soft * env;
    float as = a;
#pragma unroll
    for (int o = 32; o; o >>= 1) as += __shfl_xor(as, o);
    a = a / (as + 1e-8f);
    if (act) attnL[h][s] = a;  // exactly 0 for invalid s
    float et = a * logf(a + 1e-8f);
#pragma unroll
    for (int o = 32; o; o >>= 1) et += __shfl_xor(et, o);
    entacc += et;
  }
  if (lane == 0) entW[wv] = entacc;
  __syncthreads();
  // entropy partial: per-block store (atomic version was a 63 us serialization floor)
  if (t == 0) entpart[bx] = (entW[0] + entW[1] + entW[2] + entW[3]) * (1.f / 32768.f);
  // bf16 gather: thread t handles channels [4t,4t+4) (one uint2 / sample), head t>>5.
  // Two-chunk pipeline (17/16): all 33 loads issued before the first FMA wait.
  const u16* xbase = xb + (size_t)b * L_SEQ * 1024 + 4 * t;
  const int h = t >> 5;
  float4 acc = make_float4(0.f, 0.f, 0.f, 0.f);
  uint2 v0[17], v1[16];
#pragma unroll
  for (int k = 0; k < 17; ++k) v0[k] = *(const uint2*)(xbase + (size_t)idxL[k] * 1024);
  __builtin_amdgcn_sched_barrier(0);
#pragma unroll
  for (int k = 0; k < 16; ++k) v1[k] = *(const uint2*)(xbase + (size_t)idxL[17 + k] * 1024);
  __builtin_amdgcn_sched_barrier(0);
#pragma unroll
  for (int k = 0; k < 17; ++k) {
    const float a_ = attnL[h][k];
    acc.x += a_ * b2f(v0[k].x & 0xffffu);
    acc.y += a_ * b2f(v0[k].x >> 16);
    acc.z += a_ * b2f(v0[k].y & 0xffffu);
    acc.w += a_ * b2f(v0[k].y >> 16);
  }
  __builtin_amdgcn_sched_barrier(0);
#pragma unroll
  for (int k = 0; k < 16; ++k) {
    const float a_ = attnL[h][17 + k];
    acc.x += a_ * b2f(v1[k].x & 0xffffu);
    acc.y += a_ * b2f(v1[k].x >> 16);
    acc.z += a_ * b2f(v1[k].y & 0xffffu);
    acc.w += a_ * b2f(v1[k].y >> 16);
  }
  const size_t o4 = (size_t)row * 1024 + 4 * t;
  uint2 pk;
  pk.x = (u32)f2b(acc.x) | ((u32)f2b(acc.y) << 16);
  pk.y = (u32)f2b(acc.z) | ((u32)f2b(acc.w) << 16);
  *(uint2*)(outb + o4) = pk;
}

extern "C" void kernel_launch(void* const* d_in, const int* in_sizes, int n_in,
                              void* d_out, int out_size, void* d_ws, size_t ws_size,
                              hipStream_t stream) {
  const float* x = (const float*)d_in[0];
  const float* w_wave = (const float*)d_in[1];
  const float* b_wave = (const float*)d_in[2];
  const float* w_query = (const float*)d_in[3];
  const float* b_query = (const float*)d_in[4];
  const float* w_key = (const float*)d_in[5];
  const float* w_out = (const float*)d_in[6];
  const float* w_se1 = (const float*)d_in[7];
  const float* b_se1 = (const float*)d_in[8];
  const float* w_se2 = (const float*)d_in[9];
  const float* b_se2 = (const float*)d_in[10];
  float* out = (float*)d_out;
  char* ws = (char*)d_ws;
  size_t off = 0;
  auto alloc = [&](size_t bytes) { void* p = ws + off; off += (bytes + 255) & ~(size_t)255; return p; };
  float* params = (float*)alloc(NROWS * 18 * 4);
  float* qkbuf = (float*)alloc((size_t)NROWS * 8 * 4);
  float* entpart = (float*)alloc(NROWS * 4);
  u16* outb = (u16*)alloc((size_t)NROWS * 1024 * 2);
  u16* t1b = (u16*)alloc((size_t)NROWS * 256 * 2);
  u16* gb = (u16*)alloc((size_t)NROWS * 1024 * 2);
  u16* xb = (u16*)alloc((size_t)NROWS * 1024 * 2);
  u16* wqb = (u16*)alloc(128 * 1024 * 2);
  u16* w1b = (u16*)alloc(256 * 1024 * 2);
  u16* w2b = (u16*)alloc(1024 * 256 * 2);
  u16* wob = (u16*)alloc((size_t)1024 * 1024 * 2);
  float* entslot = out + (out_size - 1);

  // blocks [0,2048) = wave params + x->bf16; blocks [2048, 2048+1664) = weight converts
  wave_params_kernel<<<dim3(2048 + 1664), 256, 0, stream>>>(
      x, w_wave, b_wave, params, xb, w_query, w_se1, w_se2, w_out, wqb, w1b, w2b, wob);
  gemm_bt<4, 64, 32, 64><<<dim3(64, 4), 256, 0, stream>>>(
      xb, wqb, b_query, nullptr, w_key, nullptr, nullptr, qkbuf, 128, 1024);
  attn_kernel<<<dim3(NROWS), 256, 0, stream>>>(xb, params, qkbuf, outb, entpart);
  gemm_bt<1, 64, 32, 64, 1><<<dim3(64, 9), 256, 0, stream>>>(
      outb, w1b, b_se1, nullptr, nullptr, entpart, entslot, t1b, 256, 1024);
  gemm_bt<2, 128, 64, 64><<<dim3(32, 16), 256, 0, stream>>>(
      t1b, w2b, b_se2, outb, nullptr, nullptr, nullptr, gb, 1024, 256);
  gemm_bt<3, 128, 64, 64><<<dim3(32, 16), 256, 0, stream>>>(
      gb, wob, nullptr, nullptr, nullptr, nullptr, nullptr, out, 1024, 1024);
}